// Round 8
// baseline (97.250 us; speedup 1.0000x reference)
//
#include <hip/hip_runtime.h>
#include <math.h>

#define SEQ 1024
#define DM 512

typedef __attribute__((ext_vector_type(8))) short bf16x8;
typedef __attribute__((ext_vector_type(4))) short bf16x4;
typedef __attribute__((ext_vector_type(4))) float f32x4;
typedef __attribute__((ext_vector_type(4))) int i32x4;

static __device__ __forceinline__ short f2b(float f) {
    union { float f; unsigned u; } x; x.f = f;
    unsigned r = (x.u + 0x7FFFu + ((x.u >> 16) & 1u)) >> 16;
    return (short)r;
}
static __device__ __forceinline__ float b2f(short s) {
    union { unsigned u; float f; } x; x.u = ((unsigned)(unsigned short)s) << 16;
    return x.f;
}
// swizzled elem index into a [R][64] bf16 LDS tile (128B rows, XOR bank swizzle)
static __device__ __forceinline__ int sidx(int row, int col) {
    int byte = (row << 7) + (col << 1);
    byte ^= (row & 7) << 4;
    return byte >> 1;
}

static __device__ __forceinline__ void stage_f32(short* dst, const float* src, int srcStride, int tid) {
    int r = tid >> 2, c = (tid & 3) * 16;
    const float* p = src + (size_t)r * srcStride + c;
    bf16x8 v0, v1;
    #pragma unroll
    for (int e = 0; e < 8; ++e) v0[e] = f2b(p[e]);
    #pragma unroll
    for (int e = 0; e < 8; ++e) v1[e] = f2b(p[8 + e]);
    *(bf16x8*)&dst[sidx(r, c)] = v0;
    *(bf16x8*)&dst[sidx(r, c + 8)] = v1;
}
static __device__ __forceinline__ void stage_bf16(short* dst, const short* src, int srcStride, int tid) {
    int r = tid >> 2, c = (tid & 3) * 16;
    const short* p = src + (size_t)r * srcStride + c;
    bf16x8 v0 = *(const bf16x8*)p;
    bf16x8 v1 = *(const bf16x8*)(p + 8);
    *(bf16x8*)&dst[sidx(r, c)] = v0;
    *(bf16x8*)&dst[sidx(r, c + 8)] = v1;
}

// 64x64x64 MFMA block
static __device__ __forceinline__ void mma64(const short* sA, const short* sB, f32x4* acc,
                                             int w, int lr, int lg) {
    #pragma unroll
    for (int ks = 0; ks < 2; ++ks) {
        bf16x8 af = *(const bf16x8*)&sA[sidx(w * 16 + lr, ks * 32 + lg * 8)];
        #pragma unroll
        for (int nt = 0; nt < 4; ++nt) {
            bf16x8 bf = *(const bf16x8*)&sB[sidx(nt * 16 + lr, ks * 32 + lg * 8)];
            acc[nt] = __builtin_amdgcn_mfma_f32_16x16x32_bf16(af, bf, acc[nt], 0, 0, 0);
        }
    }
}

// ---------------- prep: wtrans (256 blk) + layernorm (2048 blk) + idx pack (2048 blk) ----------------
__global__ __launch_bounds__(256) void prep_kernel(
    const float* __restrict__ w0, const float* __restrict__ w1,
    const float* __restrict__ w2, const float* __restrict__ w3, short* __restrict__ wt,
    const float* __restrict__ q, float* __restrict__ qn,
    const float* __restrict__ gamma, const float* __restrict__ beta,
    const int* __restrict__ dist, const int* __restrict__ mask, unsigned char* __restrict__ idxp) {
    int blk = blockIdx.x;
    int tid = threadIdx.x;
    if (blk < 256) {
        int wsel = blk >> 6;
        int t = blk & 63;
        int tr = t >> 3, tc = t & 7;
        const float* src = wsel == 0 ? w0 : wsel == 1 ? w1 : wsel == 2 ? w2 : w3;
        short* dst = wt + (size_t)wsel * 512 * 512;
        __shared__ float tile[64][65];
        int r = tid >> 2, c = (tid & 3) * 16;
        const float* p = src + (size_t)(tr * 64 + r) * 512 + tc * 64 + c;
        #pragma unroll
        for (int e = 0; e < 16; ++e) tile[r][c + e] = p[e];
        __syncthreads();
        bf16x8 v0, v1;
        #pragma unroll
        for (int e = 0; e < 16; ++e) {
            short bv = f2b(tile[c + e][r]);
            if (e < 8) v0[e] = bv; else v1[e - 8] = bv;
        }
        short* qd = dst + (size_t)(tc * 64 + r) * 512 + tr * 64 + c;
        *(bf16x8*)qd = v0;
        *(bf16x8*)(qd + 8) = v1;
    } else if (blk < 2304) {
        int row = blk - 256;
        const float* x = q + (size_t)row * DM;
        float* y = qn + (size_t)row * DM;
        float v1 = x[tid], v2 = x[tid + 256];
        float s = v1 + v2;
        float ss = v1 * v1 + v2 * v2;
        for (int o = 32; o > 0; o >>= 1) { s += __shfl_down(s, o); ss += __shfl_down(ss, o); }
        __shared__ float red[4], red2[4];
        __shared__ float s_mu, s_rstd;
        int wid = tid >> 6, lane = tid & 63;
        if (lane == 0) { red[wid] = s; red2[wid] = ss; }
        __syncthreads();
        if (tid == 0) {
            float ts = red[0] + red[1] + red[2] + red[3];
            float tss = red2[0] + red2[1] + red2[2] + red2[3];
            float mu = ts / DM;
            float var = tss / DM - mu * mu;
            s_mu = mu;
            s_rstd = rsqrtf(var + 1e-6f);
        }
        __syncthreads();
        float mu = s_mu, rstd = s_rstd;
        y[tid]       = (v1 - mu) * rstd * gamma[tid]       + beta[tid];
        y[tid + 256] = (v2 - mu) * rstd * gamma[tid + 256] + beta[tid + 256];
    } else {
        size_t base = ((size_t)(blk - 2304) * 256 + tid) * 4;
        i32x4 dv = *(const i32x4*)(dist + base);
        i32x4 mv = *(const i32x4*)(mask + base);
        unsigned char out[4];
        #pragma unroll
        for (int e = 0; e < 4; ++e) {
            int dc = dv[e]; dc = dc > 5 ? 5 : dc;
            out[e] = (unsigned char)(dc | (mv[e] == 0 ? 8 : 0));
        }
        *(uchar4*)(idxp + base) = *(uchar4*)out;
    }
}

// ---------------- fused q/k/v projection GEMMs (768 blocks) ----------------
__global__ __launch_bounds__(256) void qkv_kernel(
    const float* __restrict__ qn, const float* __restrict__ k, const float* __restrict__ v,
    const short* __restrict__ wT, short* __restrict__ qsb, short* __restrict__ khb,
    short* __restrict__ vT) {
    __shared__ short sA[64 * 64];
    __shared__ short sB[64 * 64];
    int tid = threadIdx.x;
    int sel = blockIdx.x >> 8;
    int t = blockIdx.x & 255;
    int bx = t & 7, by = t >> 3;
    int m0 = by << 6, n0 = bx << 6;
    int w = tid >> 6, l = tid & 63;
    int lr = l & 15, lg = l >> 4;
    const float* A = sel == 0 ? qn : sel == 1 ? k : v;
    const short* Bt = wT + (size_t)sel * 262144;
    float scale = sel == 0 ? 0.125f : 1.0f;
    f32x4 acc[4] = {};
    for (int kt = 0; kt < 512; kt += 64) {
        __syncthreads();
        stage_f32(sA, A + (size_t)m0 * 512 + kt, 512, tid);
        stage_bf16(sB, Bt + (size_t)n0 * 512 + kt, 512, tid);
        __syncthreads();
        mma64(sA, sB, acc, w, lr, lg);
    }
    if (sel == 2) {
        #pragma unroll
        for (int nt = 0; nt < 4; ++nt) {
            int gn = n0 + nt * 16 + lr;
            int gm0 = m0 + w * 16 + lg * 4;
            int bq = gm0 >> 10, j0 = gm0 & 1023;
            int h = gn >> 6, dl = gn & 63;
            bf16x4 pk;
            #pragma unroll
            for (int r = 0; r < 4; ++r) pk[r] = f2b(acc[nt][r]);
            *(bf16x4*)&vT[(((size_t)((bq << 3) + h) << 6) + dl) * 1024 + j0] = pk;
        }
    } else {
        short* C = sel == 0 ? qsb : khb;
        #pragma unroll
        for (int nt = 0; nt < 4; ++nt) {
            #pragma unroll
            for (int r = 0; r < 4; ++r) {
                int gm = m0 + w * 16 + lg * 4 + r;
                int gn = n0 + nt * 16 + lr;
                C[(size_t)gm * 512 + gn] = f2b(acc[nt][r] * scale);
            }
        }
    }
}

// ---------------- single-pass fused attention ----------------
// grid: 16 bh x 64 i-tiles (16 rows), 512 threads = 8 waves.
// Waves 0-3: jt 0-7, waves 4-7: jt 8-15; strip within tile = (w&3)*16.
// Swapped QK^T (mfma(K,Q)): lane owns row i=i0+lr, 4 consecutive j.
// PV A-frag assembled via __shfl (no LDS in the j-sweep, no barriers).
__global__ __launch_bounds__(512, 8) void attn_fused_kernel(
    const short* __restrict__ qsb, const short* __restrict__ khb,
    const short* __restrict__ vT, const unsigned char* __restrict__ idxp,
    const float* __restrict__ rpr, float* __restrict__ attnp, short* __restrict__ oh) {
    int bid = blockIdx.x;
    int bh = bid >> 6, it = bid & 63;
    int b = bh >> 3, h = bh & 7;
    int i0 = it << 4;
    int tid = threadIdx.x;
    int w = tid >> 6, l = tid & 63;
    int lr = l & 15, lg = l >> 4;
    int wj = w & 3;              // j-strip within 64-col tile
    int jtb = (w >> 2) * 8;      // this wave's jt range base

    __shared__ short sQ[16 * 64];
    __shared__ float sQB[16 * 8];
    __shared__ float sL[8][16];
    __shared__ float sO[8 * 16 * 64];   // per-wave O partials [w][i][d]

    // stage Q (16x64)
    if (tid < 128) {
        int r = tid >> 3, c = (tid & 7) * 8;
        bf16x8 qv = *(const bf16x8*)(qsb + ((size_t)(b * SEQ + i0 + r)) * DM + h * 64 + c);
        *(bf16x8*)&sQ[sidx(r, c)] = qv;
    }
    __syncthreads();
    // bias table: sQB[row][m] = sum_d qs[row][d] * rpr[m][d]
    if (tid < 128) {
        int r = tid >> 3, m = tid & 7;
        if (m < 6) {
            float a = 0.f;
            #pragma unroll 8
            for (int d = 0; d < 64; ++d) a += b2f(sQ[sidx(r, d)]) * rpr[m * 64 + d];
            sQB[r * 8 + m] = a;
        }
    }
    __syncthreads();

    bf16x8 qf0 = *(const bf16x8*)&sQ[sidx(lr, lg * 8)];
    bf16x8 qf1 = *(const bf16x8*)&sQ[sidx(lr, 32 + lg * 8)];

    float l_lane = 0.f;                    // row i = i0+lr partial sum
    unsigned p_lo[8], p_hi[8];
    f32x4 accO[4] = {};
    const unsigned char* ib = idxp + ((size_t)(b * SEQ + i0 + lr)) * SEQ;
    const short* vbase = vT + ((size_t)(bh * 64)) * 1024;
    const short* kbase = khb + ((size_t)(b * SEQ)) * DM + h * 64 + lg * 8;
    const float* qbrow = sQB + lr * 8;

    #pragma unroll
    for (int jj = 0; jj < 8; ++jj) {
        int jt = jtb + jj;
        // K fragments direct from global: row j = jt*64 + wj*16 + lr
        const short* kp = kbase + (size_t)(jt * 64 + wj * 16 + lr) * DM;
        bf16x8 kf0 = *(const bf16x8*)kp;
        bf16x8 kf1 = *(const bf16x8*)(kp + 32);
        f32x4 sf = {};
        sf = __builtin_amdgcn_mfma_f32_16x16x32_bf16(kf0, qf0, sf, 0, 0, 0);   // S^T tile
        sf = __builtin_amdgcn_mfma_f32_16x16x32_bf16(kf1, qf1, sf, 0, 0, 0);
        // lane holds S[i=i0+lr][j = jt*64 + wj*16 + lg*4 + r], r=0..3
        int jcol0 = jt * 64 + wj * 16 + lg * 4;
        unsigned u = *(const unsigned*)(ib + jcol0);
        float pv[4];
        #pragma unroll
        for (int r = 0; r < 4; ++r) {
            unsigned bb = (u >> (8 * r)) & 0xffu;
            float s = fminf(sf[r] + qbrow[bb & 7], 30.f);
            float p = (bb & 8) ? 0.f : __expf(s);
            pv[r] = p;
            l_lane += p;
        }
        unsigned plo = (unsigned)(unsigned short)f2b(pv[0]) | ((unsigned)(unsigned short)f2b(pv[1]) << 16);
        unsigned phi = (unsigned)(unsigned short)f2b(pv[2]) | ((unsigned)(unsigned short)f2b(pv[3]) << 16);
        p_lo[jj] = plo; p_hi[jj] = phi;
        if (jj & 1) {
            // assemble PV A-frag for k=32 block (jt-1, jt) via cross-lane shuffles.
            // lane needs P[i=lr][m' = lg*8 .. +7]; words held by lanes lr + {0,16,32,48}.
            unsigned plo0 = p_lo[jj - 1], phi0 = p_hi[jj - 1];
            int srcA = lr + ((lg & 1) << 5);   // lg'= (lg&1)*2
            int srcB = srcA + 16;              // lg'= (lg&1)*2 + 1
            unsigned aw0 = __shfl(plo0, srcA), aw1 = __shfl(phi0, srcA);
            unsigned aw2 = __shfl(plo,  srcA), aw3 = __shfl(phi,  srcA);
            unsigned bw0 = __shfl(plo0, srcB), bw1 = __shfl(phi0, srcB);
            unsigned bw2 = __shfl(plo,  srcB), bw3 = __shfl(phi,  srcB);
            bool hi = lg >= 2;                 // lg>=2 takes jt (odd) words, else jt-1
            union { unsigned uu[4]; bf16x8 v; } afu;
            afu.uu[0] = hi ? aw2 : aw0;
            afu.uu[1] = hi ? aw3 : aw1;
            afu.uu[2] = hi ? bw2 : bw0;
            afu.uu[3] = hi ? bw3 : bw1;
            bf16x8 af = afu.v;
            int jb = (jt - 1) * 64 + (lg >> 1) * 64 + wj * 16 + (lg & 1) * 8;
            #pragma unroll
            for (int nt = 0; nt < 4; ++nt) {
                bf16x8 bf = *(const bf16x8*)(vbase + (size_t)(nt * 16 + lr) * 1024 + jb);
                accO[nt] = __builtin_amdgcn_mfma_f32_16x16x32_bf16(af, bf, accO[nt], 0, 0, 0);
            }
        }
    }

    // l reduce: sum over lg groups (lanes with same lr)
    l_lane += __shfl_xor(l_lane, 16);
    l_lane += __shfl_xor(l_lane, 32);
    if (lg == 0) sL[w][lr] = l_lane;
    // O partials: wave w block of sO
    #pragma unroll
    for (int nt = 0; nt < 4; ++nt)
        #pragma unroll
        for (int r = 0; r < 4; ++r)
            sO[w * 1024 + (lg * 4 + r) * 64 + nt * 16 + lr] = accO[nt][r];
    __syncthreads();

    // reduce O across 8 waves, normalize, write oh
    if (tid < 256) {
        int row = tid >> 4, c4 = (tid & 15) * 4;
        f32x4 o = *(f32x4*)&sO[row * 64 + c4];
        float lt = sL[0][row];
        #pragma unroll
        for (int wv = 1; wv < 8; ++wv) {
            o += *(f32x4*)&sO[wv * 1024 + row * 64 + c4];
            lt += sL[wv][row];
        }
        float rl = 1.f / lt;
        bf16x4 ob;
        #pragma unroll
        for (int e = 0; e < 4; ++e) ob[e] = f2b(o[e] * rl);
        *(bf16x4*)&oh[((size_t)(b * SEQ + i0 + row)) * DM + h * 64 + c4] = ob;
    }

    // write normalized attn: lane owns row i=i0+lr, 4 consecutive j, its 8 jts
    float lt = sL[0][lr];
    #pragma unroll
    for (int wv = 1; wv < 8; ++wv) lt += sL[wv][lr];
    float rl = 1.f / lt;
    float* ap = attnp + ((size_t)(bh * SEQ + i0 + lr)) * SEQ + wj * 16 + lg * 4;
    #pragma unroll
    for (int jj = 0; jj < 8; ++jj) {
        unsigned plo = p_lo[jj], phi = p_hi[jj];
        f32x4 o;
        o[0] = b2f((short)(plo & 0xffff)) * rl;
        o[1] = b2f((short)(plo >> 16))    * rl;
        o[2] = b2f((short)(phi & 0xffff)) * rl;
        o[3] = b2f((short)(phi >> 16))    * rl;
        *(f32x4*)&ap[(jtb + jj) * 64] = o;
    }
}

// ---------------- fc GEMM: out = oh @ w_fc^T + q ----------------
__global__ __launch_bounds__(256) void fc_kernel(
    const short* __restrict__ oh, const short* __restrict__ BtFc,
    const float* __restrict__ Rsd, float* __restrict__ Cp) {
    __shared__ short sA[64 * 64];
    __shared__ short sB[64 * 64];
    int tid = threadIdx.x;
    int bx = blockIdx.x & 7, by = blockIdx.x >> 3;
    int m0 = by << 6, n0 = bx << 6;
    int w = tid >> 6, l = tid & 63;
    int lr = l & 15, lg = l >> 4;
    f32x4 acc[4] = {};
    for (int kt = 0; kt < 512; kt += 64) {
        __syncthreads();
        stage_bf16(sA, oh + (size_t)m0 * 512 + kt, 512, tid);
        stage_bf16(sB, BtFc + (size_t)n0 * 512 + kt, 512, tid);
        __syncthreads();
        mma64(sA, sB, acc, w, lr, lg);
    }
    #pragma unroll
    for (int nt = 0; nt < 4; ++nt)
        #pragma unroll
        for (int r = 0; r < 4; ++r) {
            int gm = m0 + w * 16 + lg * 4 + r;
            int gn = n0 + nt * 16 + lr;
            Cp[(size_t)gm * 512 + gn] = acc[nt][r] + Rsd[(size_t)gm * 512 + gn];
        }
}

extern "C" void kernel_launch(void* const* d_in, const int* in_sizes, int n_in,
                              void* d_out, int out_size, void* d_ws, size_t ws_size,
                              hipStream_t stream) {
    const float* q     = (const float*)d_in[0];
    const float* k     = (const float*)d_in[1];
    const float* v     = (const float*)d_in[2];
    const int*   mask  = (const int*)d_in[3];
    const int*   dist  = (const int*)d_in[4];
    const float* w_qs  = (const float*)d_in[5];
    const float* w_ks  = (const float*)d_in[6];
    const float* w_vs  = (const float*)d_in[7];
    const float* w_fc  = (const float*)d_in[8];
    const float* gamma = (const float*)d_in[9];
    const float* beta  = (const float*)d_in[10];
    const float* rpr   = (const float*)d_in[11];

    char* wsb = (char*)d_ws;
    float* qn   = (float*)wsb;                                   // 4MB (dead after qkv)
    short* oh   = (short*)wsb;                                   // 2MB, overlays qn
    short* wT   = (short*)(wsb + 4u * 1024 * 1024);              // 2MB
    short* qsb  = (short*)(wsb + 6u * 1024 * 1024);              // 2MB
    short* khb  = (short*)(wsb + 8u * 1024 * 1024);              // 2MB
    short* vT   = (short*)(wsb + 10u * 1024 * 1024);             // 2MB
    unsigned char* idxp = (unsigned char*)(wsb + 12u * 1024 * 1024); // 2MB

    float* outp  = (float*)d_out;
    float* attnp = outp + 1048576;

    prep_kernel<<<4352, 256, 0, stream>>>(w_qs, w_ks, w_vs, w_fc, wT, q, qn, gamma, beta, dist, mask, idxp);
    qkv_kernel<<<768, 256, 0, stream>>>(qn, k, v, wT, qsb, khb, vT);
    attn_fused_kernel<<<1024, 512, 0, stream>>>(qsb, khb, vT, idxp, rpr, attnp, oh);
    fc_kernel<<<256, 256, 0, stream>>>(oh, wT + 786432, q, outp);
}

// Round 9
// 84.969 us; speedup vs baseline: 1.1445x; 1.1445x over previous
//
#include <hip/hip_runtime.h>
#include <math.h>

#define SEQ 1024
#define DM 512

typedef __attribute__((ext_vector_type(8))) short bf16x8;
typedef __attribute__((ext_vector_type(4))) short bf16x4;
typedef __attribute__((ext_vector_type(4))) float f32x4;
typedef __attribute__((ext_vector_type(4))) int i32x4;
typedef __attribute__((ext_vector_type(2))) unsigned int u32x2;

static __device__ __forceinline__ short f2b(float f) {
    union { float f; unsigned u; } x; x.f = f;
    unsigned r = (x.u + 0x7FFFu + ((x.u >> 16) & 1u)) >> 16;
    return (short)r;
}
static __device__ __forceinline__ float b2f(short s) {
    union { unsigned u; float f; } x; x.u = ((unsigned)(unsigned short)s) << 16;
    return x.f;
}
// swizzled elem index into a [R][64] bf16 LDS tile (128B rows, XOR bank swizzle)
static __device__ __forceinline__ int sidx(int row, int col) {
    int byte = (row << 7) + (col << 1);
    byte ^= (row & 7) << 4;
    return byte >> 1;
}

static __device__ __forceinline__ void stage_f32(short* dst, const float* src, int srcStride, int tid) {
    int r = tid >> 2, c = (tid & 3) * 16;
    const float* p = src + (size_t)r * srcStride + c;
    bf16x8 v0, v1;
    #pragma unroll
    for (int e = 0; e < 8; ++e) v0[e] = f2b(p[e]);
    #pragma unroll
    for (int e = 0; e < 8; ++e) v1[e] = f2b(p[8 + e]);
    *(bf16x8*)&dst[sidx(r, c)] = v0;
    *(bf16x8*)&dst[sidx(r, c + 8)] = v1;
}
static __device__ __forceinline__ void stage_bf16(short* dst, const short* src, int srcStride, int tid) {
    int r = tid >> 2, c = (tid & 3) * 16;
    const short* p = src + (size_t)r * srcStride + c;
    bf16x8 v0 = *(const bf16x8*)p;
    bf16x8 v1 = *(const bf16x8*)(p + 8);
    *(bf16x8*)&dst[sidx(r, c)] = v0;
    *(bf16x8*)&dst[sidx(r, c + 8)] = v1;
}

// 64x64x64 MFMA block
static __device__ __forceinline__ void mma64(const short* sA, const short* sB, f32x4* acc,
                                             int w, int lr, int lg) {
    #pragma unroll
    for (int ks = 0; ks < 2; ++ks) {
        bf16x8 af = *(const bf16x8*)&sA[sidx(w * 16 + lr, ks * 32 + lg * 8)];
        #pragma unroll
        for (int nt = 0; nt < 4; ++nt) {
            bf16x8 bf = *(const bf16x8*)&sB[sidx(nt * 16 + lr, ks * 32 + lg * 8)];
            acc[nt] = __builtin_amdgcn_mfma_f32_16x16x32_bf16(af, bf, acc[nt], 0, 0, 0);
        }
    }
}

// ---------------- prep: wtrans (256 blk) + layernorm (2048 blk) + idx pack (2048 blk) ----------------
__global__ __launch_bounds__(256) void prep_kernel(
    const float* __restrict__ w0, const float* __restrict__ w1,
    const float* __restrict__ w2, const float* __restrict__ w3, short* __restrict__ wt,
    const float* __restrict__ q, float* __restrict__ qn,
    const float* __restrict__ gamma, const float* __restrict__ beta,
    const int* __restrict__ dist, const int* __restrict__ mask, unsigned char* __restrict__ idxp) {
    int blk = blockIdx.x;
    int tid = threadIdx.x;
    if (blk < 256) {
        int wsel = blk >> 6;
        int t = blk & 63;
        int tr = t >> 3, tc = t & 7;
        const float* src = wsel == 0 ? w0 : wsel == 1 ? w1 : wsel == 2 ? w2 : w3;
        short* dst = wt + (size_t)wsel * 512 * 512;
        __shared__ float tile[64][65];
        int r = tid >> 2, c = (tid & 3) * 16;
        const float* p = src + (size_t)(tr * 64 + r) * 512 + tc * 64 + c;
        #pragma unroll
        for (int e = 0; e < 16; ++e) tile[r][c + e] = p[e];
        __syncthreads();
        bf16x8 v0, v1;
        #pragma unroll
        for (int e = 0; e < 16; ++e) {
            short bv = f2b(tile[c + e][r]);
            if (e < 8) v0[e] = bv; else v1[e - 8] = bv;
        }
        short* qd = dst + (size_t)(tc * 64 + r) * 512 + tr * 64 + c;
        *(bf16x8*)qd = v0;
        *(bf16x8*)(qd + 8) = v1;
    } else if (blk < 2304) {
        int row = blk - 256;
        const float* x = q + (size_t)row * DM;
        float* y = qn + (size_t)row * DM;
        float v1 = x[tid], v2 = x[tid + 256];
        float s = v1 + v2;
        float ss = v1 * v1 + v2 * v2;
        for (int o = 32; o > 0; o >>= 1) { s += __shfl_down(s, o); ss += __shfl_down(ss, o); }
        __shared__ float red[4], red2[4];
        __shared__ float s_mu, s_rstd;
        int wid = tid >> 6, lane = tid & 63;
        if (lane == 0) { red[wid] = s; red2[wid] = ss; }
        __syncthreads();
        if (tid == 0) {
            float ts = red[0] + red[1] + red[2] + red[3];
            float tss = red2[0] + red2[1] + red2[2] + red2[3];
            float mu = ts / DM;
            float var = tss / DM - mu * mu;
            s_mu = mu;
            s_rstd = rsqrtf(var + 1e-6f);
        }
        __syncthreads();
        float mu = s_mu, rstd = s_rstd;
        y[tid]       = (v1 - mu) * rstd * gamma[tid]       + beta[tid];
        y[tid + 256] = (v2 - mu) * rstd * gamma[tid + 256] + beta[tid + 256];
    } else {
        size_t base = ((size_t)(blk - 2304) * 256 + tid) * 4;
        i32x4 dv = *(const i32x4*)(dist + base);
        i32x4 mv = *(const i32x4*)(mask + base);
        unsigned char out[4];
        #pragma unroll
        for (int e = 0; e < 4; ++e) {
            int dc = dv[e]; dc = dc > 5 ? 5 : dc;
            out[e] = (unsigned char)(dc | (mv[e] == 0 ? 8 : 0));
        }
        *(uchar4*)(idxp + base) = *(uchar4*)out;
    }
}

// ---------------- fused q/k/v projection GEMMs (768 blocks) ----------------
__global__ __launch_bounds__(256) void qkv_kernel(
    const float* __restrict__ qn, const float* __restrict__ k, const float* __restrict__ v,
    const short* __restrict__ wT, short* __restrict__ qsb, short* __restrict__ khb,
    short* __restrict__ vT) {
    __shared__ short sA[64 * 64];
    __shared__ short sB[64 * 64];
    int tid = threadIdx.x;
    int sel = blockIdx.x >> 8;
    int t = blockIdx.x & 255;
    int bx = t & 7, by = t >> 3;
    int m0 = by << 6, n0 = bx << 6;
    int w = tid >> 6, l = tid & 63;
    int lr = l & 15, lg = l >> 4;
    const float* A = sel == 0 ? qn : sel == 1 ? k : v;
    const short* Bt = wT + (size_t)sel * 262144;
    float scale = sel == 0 ? 0.125f : 1.0f;
    f32x4 acc[4] = {};
    for (int kt = 0; kt < 512; kt += 64) {
        __syncthreads();
        stage_f32(sA, A + (size_t)m0 * 512 + kt, 512, tid);
        stage_bf16(sB, Bt + (size_t)n0 * 512 + kt, 512, tid);
        __syncthreads();
        mma64(sA, sB, acc, w, lr, lg);
    }
    if (sel == 2) {
        #pragma unroll
        for (int nt = 0; nt < 4; ++nt) {
            int gn = n0 + nt * 16 + lr;
            int gm0 = m0 + w * 16 + lg * 4;
            int bq = gm0 >> 10, j0 = gm0 & 1023;
            int h = gn >> 6, dl = gn & 63;
            bf16x4 pk;
            #pragma unroll
            for (int r = 0; r < 4; ++r) pk[r] = f2b(acc[nt][r]);
            *(bf16x4*)&vT[(((size_t)((bq << 3) + h) << 6) + dl) * 1024 + j0] = pk;
        }
    } else {
        short* C = sel == 0 ? qsb : khb;
        #pragma unroll
        for (int nt = 0; nt < 4; ++nt) {
            #pragma unroll
            for (int r = 0; r < 4; ++r) {
                int gm = m0 + w * 16 + lg * 4 + r;
                int gn = n0 + nt * 16 + lr;
                C[(size_t)gm * 512 + gn] = f2b(acc[nt][r] * scale);
            }
        }
    }
}

// ---------------- single-pass fused attention ----------------
// grid: 16 bh x 64 i-tiles (16 rows), 512 threads = 8 waves.
// Waves 0-3: jt 0-7, waves 4-7: jt 8-15; strip within tile = (w&3)*16.
// Swapped QK^T (mfma(K,Q)): lane owns row i=i0+lr, 4 consecutive j.
// PV A-frag via __shfl. P staged to padded LDS tile during sweep;
// epilogue writes attn with 1024B-contiguous wave stores (full lines).
#define PSTRIDE 1040   // shorts per row (1024 + 16 pad)
__global__ __launch_bounds__(512, 8) void attn_fused_kernel(
    const short* __restrict__ qsb, const short* __restrict__ khb,
    const short* __restrict__ vT, const unsigned char* __restrict__ idxp,
    const float* __restrict__ rpr, float* __restrict__ attnp, short* __restrict__ oh) {
    int bid = blockIdx.x;
    int bh = bid >> 6, it = bid & 63;
    int b = bh >> 3, h = bh & 7;
    int i0 = it << 4;
    int tid = threadIdx.x;
    int w = tid >> 6, l = tid & 63;
    int lr = l & 15, lg = l >> 4;
    int wj = w & 3;              // j-strip within 64-col tile
    int jtb = (w >> 2) * 8;      // this wave's jt range base

    __shared__ short sQ[16 * 64];
    __shared__ float sQB[16 * 8];
    __shared__ float sL[8][16];
    __shared__ float sRl[16];
    __shared__ __align__(16) char sBuf[16 * PSTRIDE * 2];  // sP bf16[16][PSTRIDE]; later sO f32[8][16][64]
    short* sP = (short*)sBuf;
    float* sO = (float*)sBuf;

    // stage Q (16x64)
    if (tid < 128) {
        int r = tid >> 3, c = (tid & 7) * 8;
        bf16x8 qv = *(const bf16x8*)(qsb + ((size_t)(b * SEQ + i0 + r)) * DM + h * 64 + c);
        *(bf16x8*)&sQ[sidx(r, c)] = qv;
    }
    __syncthreads();
    // bias table: sQB[row][m] = sum_d qs[row][d] * rpr[m][d]
    if (tid < 128) {
        int r = tid >> 3, m = tid & 7;
        if (m < 6) {
            float a = 0.f;
            #pragma unroll 8
            for (int d = 0; d < 64; ++d) a += b2f(sQ[sidx(r, d)]) * rpr[m * 64 + d];
            sQB[r * 8 + m] = a;
        }
    }
    __syncthreads();

    bf16x8 qf0 = *(const bf16x8*)&sQ[sidx(lr, lg * 8)];
    bf16x8 qf1 = *(const bf16x8*)&sQ[sidx(lr, 32 + lg * 8)];

    float l_lane = 0.f;                    // row i = i0+lr partial sum
    unsigned plo_prev = 0, phi_prev = 0;
    f32x4 accO[4] = {};
    const unsigned char* ib = idxp + ((size_t)(b * SEQ + i0 + lr)) * SEQ;
    const short* vbase = vT + ((size_t)(bh * 64)) * 1024;
    const short* kbase = khb + ((size_t)(b * SEQ)) * DM + h * 64 + lg * 8;
    const float* qbrow = sQB + lr * 8;
    short* prow = sP + lr * PSTRIDE;

    #pragma unroll
    for (int jj = 0; jj < 8; ++jj) {
        int jt = jtb + jj;
        // K fragments direct from global: row j = jt*64 + wj*16 + lr
        const short* kp = kbase + (size_t)(jt * 64 + wj * 16 + lr) * DM;
        bf16x8 kf0 = *(const bf16x8*)kp;
        bf16x8 kf1 = *(const bf16x8*)(kp + 32);
        f32x4 sf = {};
        sf = __builtin_amdgcn_mfma_f32_16x16x32_bf16(kf0, qf0, sf, 0, 0, 0);   // S^T tile
        sf = __builtin_amdgcn_mfma_f32_16x16x32_bf16(kf1, qf1, sf, 0, 0, 0);
        // lane holds S[i=i0+lr][j = jt*64 + wj*16 + lg*4 + r], r=0..3
        int jcol0 = jt * 64 + wj * 16 + lg * 4;
        unsigned u = *(const unsigned*)(ib + jcol0);
        float pv[4];
        #pragma unroll
        for (int r = 0; r < 4; ++r) {
            unsigned bb = (u >> (8 * r)) & 0xffu;
            float s = fminf(sf[r] + qbrow[bb & 7], 30.f);
            float p = (bb & 8) ? 0.f : __expf(s);
            pv[r] = p;
            l_lane += p;
        }
        unsigned plo = (unsigned)(unsigned short)f2b(pv[0]) | ((unsigned)(unsigned short)f2b(pv[1]) << 16);
        unsigned phi = (unsigned)(unsigned short)f2b(pv[2]) | ((unsigned)(unsigned short)f2b(pv[3]) << 16);
        // stash P into padded LDS row (write-only during sweep)
        {
            u32x2 pk2; pk2[0] = plo; pk2[1] = phi;
            *(u32x2*)&prow[jcol0] = pk2;
        }
        if (jj & 1) {
            // assemble PV A-frag for k=32 block (jt-1, jt) via cross-lane shuffles.
            int srcA = lr + ((lg & 1) << 5);
            int srcB = srcA + 16;
            unsigned aw0 = __shfl(plo_prev, srcA), aw1 = __shfl(phi_prev, srcA);
            unsigned aw2 = __shfl(plo,  srcA), aw3 = __shfl(phi,  srcA);
            unsigned bw0 = __shfl(plo_prev, srcB), bw1 = __shfl(phi_prev, srcB);
            unsigned bw2 = __shfl(plo,  srcB), bw3 = __shfl(phi,  srcB);
            bool hi = lg >= 2;
            union { unsigned uu[4]; bf16x8 v; } afu;
            afu.uu[0] = hi ? aw2 : aw0;
            afu.uu[1] = hi ? aw3 : aw1;
            afu.uu[2] = hi ? bw2 : bw0;
            afu.uu[3] = hi ? bw3 : bw1;
            bf16x8 af = afu.v;
            int jb = (jt - 1) * 64 + (lg >> 1) * 64 + wj * 16 + (lg & 1) * 8;
            #pragma unroll
            for (int nt = 0; nt < 4; ++nt) {
                bf16x8 bf = *(const bf16x8*)(vbase + (size_t)(nt * 16 + lr) * 1024 + jb);
                accO[nt] = __builtin_amdgcn_mfma_f32_16x16x32_bf16(af, bf, accO[nt], 0, 0, 0);
            }
        }
        plo_prev = plo; phi_prev = phi;
    }

    // l reduce: sum over lg groups (lanes with same lr)
    l_lane += __shfl_xor(l_lane, 16);
    l_lane += __shfl_xor(l_lane, 32);
    if (lg == 0) sL[w][lr] = l_lane;
    __syncthreads();                       // sP + sL complete
    if (tid < 16) {
        float lt = sL[0][tid];
        #pragma unroll
        for (int wv = 1; wv < 8; ++wv) lt += sL[wv][tid];
        sRl[tid] = 1.f / lt;
    }
    __syncthreads();

    // attn write: 8 x (64-lane f32x4) = 1024B contiguous per wave instruction
    #pragma unroll
    for (int e = 0; e < 8; ++e) {
        int chunk = e * 512 + tid;         // 0..4095
        int row = chunk >> 8;
        int c4 = (chunk & 255) * 4;
        bf16x4 pv4 = *(const bf16x4*)&sP[row * PSTRIDE + c4];
        float rl = sRl[row];
        f32x4 o;
        #pragma unroll
        for (int ee = 0; ee < 4; ++ee) o[ee] = b2f(pv4[ee]) * rl;
        *(f32x4*)&attnp[((size_t)(bh * SEQ + i0 + row)) * SEQ + c4] = o;
    }
    __syncthreads();                       // sP reads done; sBuf becomes sO

    // O partials: wave w block of sO
    #pragma unroll
    for (int nt = 0; nt < 4; ++nt)
        #pragma unroll
        for (int r = 0; r < 4; ++r)
            sO[w * 1024 + (lg * 4 + r) * 64 + nt * 16 + lr] = accO[nt][r];
    __syncthreads();

    // reduce O across 8 waves, normalize, write oh
    if (tid < 256) {
        int row = tid >> 4, c4 = (tid & 15) * 4;
        f32x4 o = *(f32x4*)&sO[row * 64 + c4];
        #pragma unroll
        for (int wv = 1; wv < 8; ++wv)
            o += *(f32x4*)&sO[wv * 1024 + row * 64 + c4];
        float rl = sRl[row];
        bf16x4 ob;
        #pragma unroll
        for (int e = 0; e < 4; ++e) ob[e] = f2b(o[e] * rl);
        *(bf16x4*)&oh[((size_t)(b * SEQ + i0 + row)) * DM + h * 64 + c4] = ob;
    }
}

// ---------------- fc GEMM: out = oh @ w_fc^T + q ----------------
__global__ __launch_bounds__(256) void fc_kernel(
    const short* __restrict__ oh, const short* __restrict__ BtFc,
    const float* __restrict__ Rsd, float* __restrict__ Cp) {
    __shared__ short sA[64 * 64];
    __shared__ short sB[64 * 64];
    int tid = threadIdx.x;
    int bx = blockIdx.x & 7, by = blockIdx.x >> 3;
    int m0 = by << 6, n0 = bx << 6;
    int w = tid >> 6, l = tid & 63;
    int lr = l & 15, lg = l >> 4;
    f32x4 acc[4] = {};
    for (int kt = 0; kt < 512; kt += 64) {
        __syncthreads();
        stage_bf16(sA, oh + (size_t)m0 * 512 + kt, 512, tid);
        stage_bf16(sB, BtFc + (size_t)n0 * 512 + kt, 512, tid);
        __syncthreads();
        mma64(sA, sB, acc, w, lr, lg);
    }
    #pragma unroll
    for (int nt = 0; nt < 4; ++nt)
        #pragma unroll
        for (int r = 0; r < 4; ++r) {
            int gm = m0 + w * 16 + lg * 4 + r;
            int gn = n0 + nt * 16 + lr;
            Cp[(size_t)gm * 512 + gn] = acc[nt][r] + Rsd[(size_t)gm * 512 + gn];
        }
}

extern "C" void kernel_launch(void* const* d_in, const int* in_sizes, int n_in,
                              void* d_out, int out_size, void* d_ws, size_t ws_size,
                              hipStream_t stream) {
    const float* q     = (const float*)d_in[0];
    const float* k     = (const float*)d_in[1];
    const float* v     = (const float*)d_in[2];
    const int*   mask  = (const int*)d_in[3];
    const int*   dist  = (const int*)d_in[4];
    const float* w_qs  = (const float*)d_in[5];
    const float* w_ks  = (const float*)d_in[6];
    const float* w_vs  = (const float*)d_in[7];
    const float* w_fc  = (const float*)d_in[8];
    const float* gamma = (const float*)d_in[9];
    const float* beta  = (const float*)d_in[10];
    const float* rpr   = (const float*)d_in[11];

    char* wsb = (char*)d_ws;
    float* qn   = (float*)wsb;                                   // 4MB (dead after qkv)
    short* oh   = (short*)wsb;                                   // 2MB, overlays qn
    short* wT   = (short*)(wsb + 4u * 1024 * 1024);              // 2MB
    short* qsb  = (short*)(wsb + 6u * 1024 * 1024);              // 2MB
    short* khb  = (short*)(wsb + 8u * 1024 * 1024);              // 2MB
    short* vT   = (short*)(wsb + 10u * 1024 * 1024);             // 2MB
    unsigned char* idxp = (unsigned char*)(wsb + 12u * 1024 * 1024); // 2MB

    float* outp  = (float*)d_out;
    float* attnp = outp + 1048576;

    prep_kernel<<<4352, 256, 0, stream>>>(w_qs, w_ks, w_vs, w_fc, wT, q, qn, gamma, beta, dist, mask, idxp);
    qkv_kernel<<<768, 256, 0, stream>>>(qn, k, v, wT, qsb, khb, vT);
    attn_fused_kernel<<<1024, 512, 0, stream>>>(qsb, khb, vT, idxp, rpr, attnp, oh);
    fc_kernel<<<256, 256, 0, stream>>>(oh, wT + 786432, q, outp);
}

// Round 10
// 84.349 us; speedup vs baseline: 1.1529x; 1.0073x over previous
//
#include <hip/hip_runtime.h>
#include <math.h>

#define SEQ 1024
#define DM 512

typedef __attribute__((ext_vector_type(8))) short bf16x8;
typedef __attribute__((ext_vector_type(4))) short bf16x4;
typedef __attribute__((ext_vector_type(4))) float f32x4;
typedef __attribute__((ext_vector_type(4))) int i32x4;
typedef __attribute__((ext_vector_type(2))) unsigned int u32x2;

static __device__ __forceinline__ short f2b(float f) {
    union { float f; unsigned u; } x; x.f = f;
    unsigned r = (x.u + 0x7FFFu + ((x.u >> 16) & 1u)) >> 16;
    return (short)r;
}
static __device__ __forceinline__ float b2f(short s) {
    union { unsigned u; float f; } x; x.u = ((unsigned)(unsigned short)s) << 16;
    return x.f;
}
// swizzled elem index into a [R][64] bf16 LDS tile (128B rows, XOR bank swizzle)
static __device__ __forceinline__ int sidx(int row, int col) {
    int byte = (row << 7) + (col << 1);
    byte ^= (row & 7) << 4;
    return byte >> 1;
}

static __device__ __forceinline__ void stage_f32(short* dst, const float* src, int srcStride, int tid) {
    int r = tid >> 2, c = (tid & 3) * 16;
    const float* p = src + (size_t)r * srcStride + c;
    bf16x8 v0, v1;
    #pragma unroll
    for (int e = 0; e < 8; ++e) v0[e] = f2b(p[e]);
    #pragma unroll
    for (int e = 0; e < 8; ++e) v1[e] = f2b(p[8 + e]);
    *(bf16x8*)&dst[sidx(r, c)] = v0;
    *(bf16x8*)&dst[sidx(r, c + 8)] = v1;
}
static __device__ __forceinline__ void stage_bf16(short* dst, const short* src, int srcStride, int tid) {
    int r = tid >> 2, c = (tid & 3) * 16;
    const short* p = src + (size_t)r * srcStride + c;
    bf16x8 v0 = *(const bf16x8*)p;
    bf16x8 v1 = *(const bf16x8*)(p + 8);
    *(bf16x8*)&dst[sidx(r, c)] = v0;
    *(bf16x8*)&dst[sidx(r, c + 8)] = v1;
}

// 64x64x64 MFMA block
static __device__ __forceinline__ void mma64(const short* sA, const short* sB, f32x4* acc,
                                             int w, int lr, int lg) {
    #pragma unroll
    for (int ks = 0; ks < 2; ++ks) {
        bf16x8 af = *(const bf16x8*)&sA[sidx(w * 16 + lr, ks * 32 + lg * 8)];
        #pragma unroll
        for (int nt = 0; nt < 4; ++nt) {
            bf16x8 bf = *(const bf16x8*)&sB[sidx(nt * 16 + lr, ks * 32 + lg * 8)];
            acc[nt] = __builtin_amdgcn_mfma_f32_16x16x32_bf16(af, bf, acc[nt], 0, 0, 0);
        }
    }
}

// ---------------- prep: wtrans (256 blk) + layernorm (2048 blk) + idx pack (2048 blk) ----------------
__global__ __launch_bounds__(256) void prep_kernel(
    const float* __restrict__ w0, const float* __restrict__ w1,
    const float* __restrict__ w2, const float* __restrict__ w3, short* __restrict__ wt,
    const float* __restrict__ q, float* __restrict__ qn,
    const float* __restrict__ gamma, const float* __restrict__ beta,
    const int* __restrict__ dist, const int* __restrict__ mask, unsigned char* __restrict__ idxp) {
    int blk = blockIdx.x;
    int tid = threadIdx.x;
    if (blk < 256) {
        int wsel = blk >> 6;
        int t = blk & 63;
        int tr = t >> 3, tc = t & 7;
        const float* src = wsel == 0 ? w0 : wsel == 1 ? w1 : wsel == 2 ? w2 : w3;
        short* dst = wt + (size_t)wsel * 512 * 512;
        __shared__ float tile[64][65];
        int r = tid >> 2, c = (tid & 3) * 16;
        const float* p = src + (size_t)(tr * 64 + r) * 512 + tc * 64 + c;
        #pragma unroll
        for (int e = 0; e < 16; ++e) tile[r][c + e] = p[e];
        __syncthreads();
        bf16x8 v0, v1;
        #pragma unroll
        for (int e = 0; e < 16; ++e) {
            short bv = f2b(tile[c + e][r]);
            if (e < 8) v0[e] = bv; else v1[e - 8] = bv;
        }
        short* qd = dst + (size_t)(tc * 64 + r) * 512 + tr * 64 + c;
        *(bf16x8*)qd = v0;
        *(bf16x8*)(qd + 8) = v1;
    } else if (blk < 2304) {
        int row = blk - 256;
        const float* x = q + (size_t)row * DM;
        float* y = qn + (size_t)row * DM;
        float v1 = x[tid], v2 = x[tid + 256];
        float s = v1 + v2;
        float ss = v1 * v1 + v2 * v2;
        for (int o = 32; o > 0; o >>= 1) { s += __shfl_down(s, o); ss += __shfl_down(ss, o); }
        __shared__ float red[4], red2[4];
        __shared__ float s_mu, s_rstd;
        int wid = tid >> 6, lane = tid & 63;
        if (lane == 0) { red[wid] = s; red2[wid] = ss; }
        __syncthreads();
        if (tid == 0) {
            float ts = red[0] + red[1] + red[2] + red[3];
            float tss = red2[0] + red2[1] + red2[2] + red2[3];
            float mu = ts / DM;
            float var = tss / DM - mu * mu;
            s_mu = mu;
            s_rstd = rsqrtf(var + 1e-6f);
        }
        __syncthreads();
        float mu = s_mu, rstd = s_rstd;
        y[tid]       = (v1 - mu) * rstd * gamma[tid]       + beta[tid];
        y[tid + 256] = (v2 - mu) * rstd * gamma[tid + 256] + beta[tid + 256];
    } else {
        size_t base = ((size_t)(blk - 2304) * 256 + tid) * 4;
        i32x4 dv = *(const i32x4*)(dist + base);
        i32x4 mv = *(const i32x4*)(mask + base);
        unsigned char out[4];
        #pragma unroll
        for (int e = 0; e < 4; ++e) {
            int dc = dv[e]; dc = dc > 5 ? 5 : dc;
            out[e] = (unsigned char)(dc | (mv[e] == 0 ? 8 : 0));
        }
        *(uchar4*)(idxp + base) = *(uchar4*)out;
    }
}

// ---------------- fused q/k/v projection GEMMs (768 blocks) ----------------
__global__ __launch_bounds__(256) void qkv_kernel(
    const float* __restrict__ qn, const float* __restrict__ k, const float* __restrict__ v,
    const short* __restrict__ wT, short* __restrict__ qsb, short* __restrict__ khb,
    short* __restrict__ vT) {
    __shared__ short sA[64 * 64];
    __shared__ short sB[64 * 64];
    int tid = threadIdx.x;
    int sel = blockIdx.x >> 8;
    int t = blockIdx.x & 255;
    int bx = t & 7, by = t >> 3;
    int m0 = by << 6, n0 = bx << 6;
    int w = tid >> 6, l = tid & 63;
    int lr = l & 15, lg = l >> 4;
    const float* A = sel == 0 ? qn : sel == 1 ? k : v;
    const short* Bt = wT + (size_t)sel * 262144;
    float scale = sel == 0 ? 0.125f : 1.0f;
    f32x4 acc[4] = {};
    for (int kt = 0; kt < 512; kt += 64) {
        __syncthreads();
        stage_f32(sA, A + (size_t)m0 * 512 + kt, 512, tid);
        stage_bf16(sB, Bt + (size_t)n0 * 512 + kt, 512, tid);
        __syncthreads();
        mma64(sA, sB, acc, w, lr, lg);
    }
    if (sel == 2) {
        #pragma unroll
        for (int nt = 0; nt < 4; ++nt) {
            int gn = n0 + nt * 16 + lr;
            int gm0 = m0 + w * 16 + lg * 4;
            int bq = gm0 >> 10, j0 = gm0 & 1023;
            int h = gn >> 6, dl = gn & 63;
            bf16x4 pk;
            #pragma unroll
            for (int r = 0; r < 4; ++r) pk[r] = f2b(acc[nt][r]);
            *(bf16x4*)&vT[(((size_t)((bq << 3) + h) << 6) + dl) * 1024 + j0] = pk;
        }
    } else {
        short* C = sel == 0 ? qsb : khb;
        #pragma unroll
        for (int nt = 0; nt < 4; ++nt) {
            #pragma unroll
            for (int r = 0; r < 4; ++r) {
                int gm = m0 + w * 16 + lg * 4 + r;
                int gn = n0 + nt * 16 + lr;
                C[(size_t)gm * 512 + gn] = f2b(acc[nt][r] * scale);
            }
        }
    }
}

// ---------------- single-pass fused attention ----------------
// grid: 16 bh x 64 i-tiles (16 rows), 512 threads = 8 waves.
// Waves 0-3: jt 0-7, waves 4-7: jt 8-15; strip within tile = (w&3)*16.
// Swapped QK^T (mfma(K,Q)): lane owns row i=i0+lr, 4 consecutive j.
// PV A-frag via __shfl. P staged to padded LDS tile during sweep;
// epilogue writes attn with 1024B-contiguous wave stores (full lines).
// EXPLICIT PREFETCH: next-iter K+idx and pair V issued before the exp chain.
#define PSTRIDE 1040   // shorts per row (1024 + 16 pad)
__global__ __launch_bounds__(512, 4) void attn_fused_kernel(
    const short* __restrict__ qsb, const short* __restrict__ khb,
    const short* __restrict__ vT, const unsigned char* __restrict__ idxp,
    const float* __restrict__ rpr, float* __restrict__ attnp, short* __restrict__ oh) {
    int bid = blockIdx.x;
    int bh = bid >> 6, it = bid & 63;
    int b = bh >> 3, h = bh & 7;
    int i0 = it << 4;
    int tid = threadIdx.x;
    int w = tid >> 6, l = tid & 63;
    int lr = l & 15, lg = l >> 4;
    int wj = w & 3;              // j-strip within 64-col tile
    int jtb = (w >> 2) * 8;      // this wave's jt range base

    __shared__ short sQ[16 * 64];
    __shared__ float sQB[16 * 8];
    __shared__ float sL[8][16];
    __shared__ float sRl[16];
    __shared__ __align__(16) char sBuf[16 * PSTRIDE * 2];  // sP bf16[16][PSTRIDE]; later sO f32[8][16][64]
    short* sP = (short*)sBuf;
    float* sO = (float*)sBuf;

    // stage Q (16x64)
    if (tid < 128) {
        int r = tid >> 3, c = (tid & 7) * 8;
        bf16x8 qv = *(const bf16x8*)(qsb + ((size_t)(b * SEQ + i0 + r)) * DM + h * 64 + c);
        *(bf16x8*)&sQ[sidx(r, c)] = qv;
    }
    __syncthreads();
    // bias table: sQB[row][m] = sum_d qs[row][d] * rpr[m][d]
    if (tid < 128) {
        int r = tid >> 3, m = tid & 7;
        if (m < 6) {
            float a = 0.f;
            #pragma unroll 8
            for (int d = 0; d < 64; ++d) a += b2f(sQ[sidx(r, d)]) * rpr[m * 64 + d];
            sQB[r * 8 + m] = a;
        }
    }
    __syncthreads();

    bf16x8 qf0 = *(const bf16x8*)&sQ[sidx(lr, lg * 8)];
    bf16x8 qf1 = *(const bf16x8*)&sQ[sidx(lr, 32 + lg * 8)];

    float l_lane = 0.f;                    // row i = i0+lr partial sum
    unsigned plo_prev = 0, phi_prev = 0;
    f32x4 accO[4] = {};
    const unsigned char* ib = idxp + ((size_t)(b * SEQ + i0 + lr)) * SEQ;
    const short* vbase = vT + ((size_t)(bh * 64)) * 1024;
    const short* kbase = khb + ((size_t)(b * SEQ)) * DM + h * 64 + lg * 8;
    const float* qbrow = sQB + lr * 8;
    short* prow = sP + lr * PSTRIDE;

    // prime iteration 0's K + idx
    bf16x8 kf0, kf1, vf0, vf1, vf2, vf3;
    unsigned u;
    {
        const short* kp = kbase + (size_t)(jtb * 64 + wj * 16 + lr) * DM;
        kf0 = *(const bf16x8*)kp;
        kf1 = *(const bf16x8*)(kp + 32);
        u = *(const unsigned*)(ib + jtb * 64 + wj * 16 + lg * 4);
    }

    #pragma unroll
    for (int jj = 0; jj < 8; ++jj) {
        int jt = jtb + jj;
        // prefetch next iteration's K fragments + idx word
        bf16x8 kf0n, kf1n;
        unsigned un;
        if (jj < 7) {
            const short* kp = kbase + (size_t)((jt + 1) * 64 + wj * 16 + lr) * DM;
            kf0n = *(const bf16x8*)kp;
            kf1n = *(const bf16x8*)(kp + 32);
            un = *(const unsigned*)(ib + (jt + 1) * 64 + wj * 16 + lg * 4);
        }
        // prefetch this pair's V fragments at pair start (used at odd jj)
        if (!(jj & 1)) {
            int jb = jt * 64 + (lg >> 1) * 64 + wj * 16 + (lg & 1) * 8;
            vf0 = *(const bf16x8*)(vbase + (size_t)(0 * 16 + lr) * 1024 + jb);
            vf1 = *(const bf16x8*)(vbase + (size_t)(1 * 16 + lr) * 1024 + jb);
            vf2 = *(const bf16x8*)(vbase + (size_t)(2 * 16 + lr) * 1024 + jb);
            vf3 = *(const bf16x8*)(vbase + (size_t)(3 * 16 + lr) * 1024 + jb);
        }
        f32x4 sf = {};
        sf = __builtin_amdgcn_mfma_f32_16x16x32_bf16(kf0, qf0, sf, 0, 0, 0);   // S^T tile
        sf = __builtin_amdgcn_mfma_f32_16x16x32_bf16(kf1, qf1, sf, 0, 0, 0);
        // lane holds S[i=i0+lr][j = jt*64 + wj*16 + lg*4 + r], r=0..3
        int jcol0 = jt * 64 + wj * 16 + lg * 4;
        float pv[4];
        #pragma unroll
        for (int r = 0; r < 4; ++r) {
            unsigned bb = (u >> (8 * r)) & 0xffu;
            float s = fminf(sf[r] + qbrow[bb & 7], 30.f);
            float p = (bb & 8) ? 0.f : __expf(s);
            pv[r] = p;
            l_lane += p;
        }
        unsigned plo = (unsigned)(unsigned short)f2b(pv[0]) | ((unsigned)(unsigned short)f2b(pv[1]) << 16);
        unsigned phi = (unsigned)(unsigned short)f2b(pv[2]) | ((unsigned)(unsigned short)f2b(pv[3]) << 16);
        // stash P into padded LDS row (write-only during sweep)
        {
            u32x2 pk2; pk2[0] = plo; pk2[1] = phi;
            *(u32x2*)&prow[jcol0] = pk2;
        }
        if (jj & 1) {
            // assemble PV A-frag for k=32 block (jt-1, jt) via cross-lane shuffles.
            int srcA = lr + ((lg & 1) << 5);
            int srcB = srcA + 16;
            unsigned aw0 = __shfl(plo_prev, srcA), aw1 = __shfl(phi_prev, srcA);
            unsigned aw2 = __shfl(plo,  srcA), aw3 = __shfl(phi,  srcA);
            unsigned bw0 = __shfl(plo_prev, srcB), bw1 = __shfl(phi_prev, srcB);
            unsigned bw2 = __shfl(plo,  srcB), bw3 = __shfl(phi,  srcB);
            bool hi = lg >= 2;
            union { unsigned uu[4]; bf16x8 v; } afu;
            afu.uu[0] = hi ? aw2 : aw0;
            afu.uu[1] = hi ? aw3 : aw1;
            afu.uu[2] = hi ? bw2 : bw0;
            afu.uu[3] = hi ? bw3 : bw1;
            bf16x8 af = afu.v;
            accO[0] = __builtin_amdgcn_mfma_f32_16x16x32_bf16(af, vf0, accO[0], 0, 0, 0);
            accO[1] = __builtin_amdgcn_mfma_f32_16x16x32_bf16(af, vf1, accO[1], 0, 0, 0);
            accO[2] = __builtin_amdgcn_mfma_f32_16x16x32_bf16(af, vf2, accO[2], 0, 0, 0);
            accO[3] = __builtin_amdgcn_mfma_f32_16x16x32_bf16(af, vf3, accO[3], 0, 0, 0);
        }
        plo_prev = plo; phi_prev = phi;
        kf0 = kf0n; kf1 = kf1n; u = un;
    }

    // l reduce: sum over lg groups (lanes with same lr)
    l_lane += __shfl_xor(l_lane, 16);
    l_lane += __shfl_xor(l_lane, 32);
    if (lg == 0) sL[w][lr] = l_lane;
    __syncthreads();                       // sP + sL complete
    if (tid < 16) {
        float lt = sL[0][tid];
        #pragma unroll
        for (int wv = 1; wv < 8; ++wv) lt += sL[wv][tid];
        sRl[tid] = 1.f / lt;
    }
    __syncthreads();

    // attn write: 8 x (64-lane f32x4) = 1024B contiguous per wave instruction
    #pragma unroll
    for (int e = 0; e < 8; ++e) {
        int chunk = e * 512 + tid;         // 0..4095
        int row = chunk >> 8;
        int c4 = (chunk & 255) * 4;
        bf16x4 pv4 = *(const bf16x4*)&sP[row * PSTRIDE + c4];
        float rl = sRl[row];
        f32x4 o;
        #pragma unroll
        for (int ee = 0; ee < 4; ++ee) o[ee] = b2f(pv4[ee]) * rl;
        *(f32x4*)&attnp[((size_t)(bh * SEQ + i0 + row)) * SEQ + c4] = o;
    }
    __syncthreads();                       // sP reads done; sBuf becomes sO

    // O partials: wave w block of sO
    #pragma unroll
    for (int nt = 0; nt < 4; ++nt)
        #pragma unroll
        for (int r = 0; r < 4; ++r)
            sO[w * 1024 + (lg * 4 + r) * 64 + nt * 16 + lr] = accO[nt][r];
    __syncthreads();

    // reduce O across 8 waves, normalize, write oh
    if (tid < 256) {
        int row = tid >> 4, c4 = (tid & 15) * 4;
        f32x4 o = *(f32x4*)&sO[row * 64 + c4];
        #pragma unroll
        for (int wv = 1; wv < 8; ++wv)
            o += *(f32x4*)&sO[wv * 1024 + row * 64 + c4];
        float rl = sRl[row];
        bf16x4 ob;
        #pragma unroll
        for (int e = 0; e < 4; ++e) ob[e] = f2b(o[e] * rl);
        *(bf16x4*)&oh[((size_t)(b * SEQ + i0 + row)) * DM + h * 64 + c4] = ob;
    }
}

// ---------------- fc GEMM: out = oh @ w_fc^T + q ----------------
__global__ __launch_bounds__(256) void fc_kernel(
    const short* __restrict__ oh, const short* __restrict__ BtFc,
    const float* __restrict__ Rsd, float* __restrict__ Cp) {
    __shared__ short sA[64 * 64];
    __shared__ short sB[64 * 64];
    int tid = threadIdx.x;
    int bx = blockIdx.x & 7, by = blockIdx.x >> 3;
    int m0 = by << 6, n0 = bx << 6;
    int w = tid >> 6, l = tid & 63;
    int lr = l & 15, lg = l >> 4;
    f32x4 acc[4] = {};
    for (int kt = 0; kt < 512; kt += 64) {
        __syncthreads();
        stage_bf16(sA, oh + (size_t)m0 * 512 + kt, 512, tid);
        stage_bf16(sB, BtFc + (size_t)n0 * 512 + kt, 512, tid);
        __syncthreads();
        mma64(sA, sB, acc, w, lr, lg);
    }
    #pragma unroll
    for (int nt = 0; nt < 4; ++nt)
        #pragma unroll
        for (int r = 0; r < 4; ++r) {
            int gm = m0 + w * 16 + lg * 4 + r;
            int gn = n0 + nt * 16 + lr;
            Cp[(size_t)gm * 512 + gn] = acc[nt][r] + Rsd[(size_t)gm * 512 + gn];
        }
}

extern "C" void kernel_launch(void* const* d_in, const int* in_sizes, int n_in,
                              void* d_out, int out_size, void* d_ws, size_t ws_size,
                              hipStream_t stream) {
    const float* q     = (const float*)d_in[0];
    const float* k     = (const float*)d_in[1];
    const float* v     = (const float*)d_in[2];
    const int*   mask  = (const int*)d_in[3];
    const int*   dist  = (const int*)d_in[4];
    const float* w_qs  = (const float*)d_in[5];
    const float* w_ks  = (const float*)d_in[6];
    const float* w_vs  = (const float*)d_in[7];
    const float* w_fc  = (const float*)d_in[8];
    const float* gamma = (const float*)d_in[9];
    const float* beta  = (const float*)d_in[10];
    const float* rpr   = (const float*)d_in[11];

    char* wsb = (char*)d_ws;
    float* qn   = (float*)wsb;                                   // 4MB (dead after qkv)
    short* oh   = (short*)wsb;                                   // 2MB, overlays qn
    short* wT   = (short*)(wsb + 4u * 1024 * 1024);              // 2MB
    short* qsb  = (short*)(wsb + 6u * 1024 * 1024);              // 2MB
    short* khb  = (short*)(wsb + 8u * 1024 * 1024);              // 2MB
    short* vT   = (short*)(wsb + 10u * 1024 * 1024);             // 2MB
    unsigned char* idxp = (unsigned char*)(wsb + 12u * 1024 * 1024); // 2MB

    float* outp  = (float*)d_out;
    float* attnp = outp + 1048576;

    prep_kernel<<<4352, 256, 0, stream>>>(w_qs, w_ks, w_vs, w_fc, wT, q, qn, gamma, beta, dist, mask, idxp);
    qkv_kernel<<<768, 256, 0, stream>>>(qn, k, v, wT, qsb, khb, vT);
    attn_fused_kernel<<<1024, 512, 0, stream>>>(qsb, khb, vT, idxp, rpr, attnp, oh);
    fc_kernel<<<256, 256, 0, stream>>>(oh, wT + 786432, q, outp);
}